// Round 6
// baseline (793.052 us; speedup 1.0000x reference)
//
#include <hip/hip_runtime.h>

// AdaTTSp on MI355X. B=32768, T=8, E=2, NE=16, D=H=128, L=2.
// Round 6: fully fused per-layer kernel. Block = 32 batch rows, 1024 thr
// (16 waves). Gates via split-bf16 MFMA + shfl softmax -> LDS; then per
// expert: GEMM1 -> h (LDS bf16 pair) -> GEMM2 -> eo (LDS f32) -> VALU
// accumulate gates*eo + sew*eo into registers. eo NEVER goes to HBM.
// HBM/layer: x read 2x (gate pass + expert pass) + fused write = 384MB.
// Split precision: every f32 operand -> bf16 hi+lo, 3 MFMAs/term (round-5
// validated, absmax 9.8e-4). Launches: kxform + 2 kfused.

typedef float f32x4 __attribute__((ext_vector_type(4)));
typedef short s16x8 __attribute__((ext_vector_type(8)));
typedef unsigned short u16;
typedef u16 u16x4 __attribute__((ext_vector_type(4)));

#define MFMA(a, b, c) __builtin_amdgcn_mfma_f32_16x16x32_bf16(a, b, c, 0, 0, 0)

__device__ __forceinline__ u16 f2bf(float f) {
  unsigned u = __builtin_bit_cast(unsigned, f);
  return (u16)((u + 0x7FFFu + ((u >> 16) & 1u)) >> 16);  // RNE
}
__device__ __forceinline__ float bf2f(u16 b) {
  unsigned u = ((unsigned)b) << 16;
  return __builtin_bit_cast(float, u);
}
__device__ __forceinline__ void split2(float f, u16& h, u16& l) {
  h = f2bf(f);
  l = f2bf(f - bf2f(h));
}

// ---------------------------------------------------------------------------
// Weight transform -> hi/lo bf16 fragment arrays.
// w1T/w2T: [q=l*16+e][ks][it][lane][j] (lo at +524288 elems)
//   elem = w[q][d = 32*ks + 8*(lane>>4) + j][m = 16*it + (lane&15)]
// gwT: [q=l*8+t][ks][lane][j] (lo at +32768)
//   elem = gw[q][d = 32*ks + 8*(lane>>4) + j][e = lane&15]
__global__ __launch_bounds__(256) void kxform(
    const float* __restrict__ w1, const float* __restrict__ w2,
    const float* __restrict__ gw, u16* __restrict__ w1T,
    u16* __restrict__ w2T, u16* __restrict__ gwT) {
  int idx = blockIdx.x * 256 + threadIdx.x;
  if (idx < 131072) {
    const float* src = (idx < 65536) ? w1 : w2;
    u16* dst = (idx < 65536) ? w1T : w2T;
    int i = idx & 65535;
    int lane = i & 63;
    int it = (i >> 6) & 7;
    int ks = (i >> 9) & 3;
    int q = i >> 11;
    int g = lane >> 4, le = lane & 15;
    s16x8 vh, vl;
#pragma unroll
    for (int j = 0; j < 8; ++j) {
      float f = src[((size_t)q * 128 + (32 * ks + 8 * g + j)) * 128 + 16 * it + le];
      u16 h, l;
      split2(f, h, l);
      vh[j] = (short)h;
      vl[j] = (short)l;
    }
    *(s16x8*)(dst + (size_t)i * 8) = vh;
    *(s16x8*)(dst + 524288 + (size_t)i * 8) = vl;
  } else {
    int i = idx - 131072;  // 0..4095
    if (i >= 4096) return;
    int lane = i & 63;
    int ks = (i >> 6) & 3;
    int q = (i >> 8) & 15;
    int g = lane >> 4, le = lane & 15;
    s16x8 vh, vl;
#pragma unroll
    for (int j = 0; j < 8; ++j) {
      float f = gw[((size_t)q * 128 + (32 * ks + 8 * g + j)) * 16 + le];
      u16 h, l;
      split2(f, h, l);
      vh[j] = (short)h;
      vl[j] = (short)l;
    }
    *(s16x8*)(gwT + (size_t)i * 8) = vh;
    *(s16x8*)(gwT + 32768 + (size_t)i * 8) = vl;
  }
}

// ---------------------------------------------------------------------------
// Fused layer kernel. grid = B/32 = 1024 blocks, 1024 threads (16 waves).
// Wave -> (it = wave>>1: M-tile of 8, jn = wave&1: N-tile of 2).
// LDS tiles (x and h swizzle: elem [row][c] at
//   row*128 + 8*((c>>3)^(row&7)) + (c&7); eo f32 granule-4 XOR).
__global__ __launch_bounds__(1024) void kfused(
    const float* __restrict__ xin, float* __restrict__ xout,
    const u16* __restrict__ w1T, const u16* __restrict__ w2T,
    const u16* __restrict__ gwT, const float* __restrict__ b1,
    const float* __restrict__ b2, const float* __restrict__ gb,
    const float* __restrict__ sw, int layer) {
  __shared__ u16 sXh[32 * 128], sXl[32 * 128];
  __shared__ u16 sHh[32 * 128], sHl[32 * 128];
  __shared__ float sEO[32 * 128];
  __shared__ float sG[8 * 16 * 32];  // [t][e][b]
  const int tid = threadIdx.x;
  const int lane = tid & 63;
  const int wave = tid >> 6;
  const int g = lane >> 4, le = lane & 15;
  const int it = wave >> 1, jn = wave & 1;
  const int r0 = blockIdx.x * 32;
  const int srow = tid >> 5, sc4 = tid & 31;  // staging map
  const int ab = tid >> 5, ac4 = tid & 31;    // accum map

  const int brow = jn * 16 + le;
  const int bsa = (brow * 16);  // row base for b-frag reads

#define STAGE_SLICE(T)                                                        \
  {                                                                           \
    f32x4 xv = *(const f32x4*)(xin + ((size_t)(r0 + srow) * 8 + (T)) * 128 +  \
                               sc4 * 4);                                      \
    u16x4 vh, vl;                                                             \
    _Pragma("unroll") for (int z = 0; z < 4; ++z) {                           \
      u16 h_, l_;                                                             \
      split2(xv[z], h_, l_);                                                  \
      vh[z] = h_;                                                             \
      vl[z] = l_;                                                             \
    }                                                                         \
    int sa_ = srow * 128 + 8 * ((sc4 >> 1) ^ (srow & 7)) + 4 * (sc4 & 1);     \
    *(u16x4*)(sXh + sa_) = vh;                                                \
    *(u16x4*)(sXl + sa_) = vl;                                                \
  }

  // ---------- Phase A: gates ----------
  for (int t = 0; t < 8; ++t) {
    STAGE_SLICE(t);
    __syncthreads();
    if (it == t) {  // two waves (jn = 0,1) compute this task's gates
      const int lt = layer * 8 + t;
      f32x4 acc = f32x4{0.f, 0.f, 0.f, 0.f};
#pragma unroll
      for (int ks = 0; ks < 4; ++ks) {
        size_t fb = ((size_t)(lt * 4 + ks) * 64 + lane) * 8;
        s16x8 ah = *(const s16x8*)(gwT + fb);
        s16x8 al = *(const s16x8*)(gwT + 32768 + fb);
        int sa = (bsa + ((4 * ks + g) ^ (brow & 7))) * 8;
        s16x8 bh = *(const s16x8*)(sXh + sa);
        s16x8 bl = *(const s16x8*)(sXl + sa);
        acc = MFMA(al, bh, acc);
        acc = MFMA(ah, bl, acc);
        acc = MFMA(ah, bh, acc);
      }
      float zb[4];
#pragma unroll
      for (int r = 0; r < 4; ++r) zb[r] = acc[r] + gb[lt * 16 + 4 * g + r];
      float m4 = fmaxf(fmaxf(zb[0], zb[1]), fmaxf(zb[2], zb[3]));
      m4 = fmaxf(m4, __shfl_xor(m4, 16, 64));
      m4 = fmaxf(m4, __shfl_xor(m4, 32, 64));
      float p[4], s4 = 0.f;
#pragma unroll
      for (int r = 0; r < 4; ++r) {
        p[r] = __expf(zb[r] - m4);
        s4 += p[r];
      }
      s4 += __shfl_xor(s4, 16, 64);
      s4 += __shfl_xor(s4, 32, 64);
      float inv = 1.f / s4;
#pragma unroll
      for (int r = 0; r < 4; ++r)
        sG[(t * 16 + 4 * g + r) * 32 + brow] = p[r] * inv;
    }
    __syncthreads();  // gate reads of sX done before next stage overwrites
  }

  // persistent fused accumulators: thread (ab, ac4) owns cols ac4*4..+3, all t
  f32x4 accf[8];
#pragma unroll
  for (int t = 0; t < 8; ++t) accf[t] = f32x4{0.f, 0.f, 0.f, 0.f};

  // ---------- Phase B: experts ----------
  for (int te = 0; te < 8; ++te) {
    STAGE_SLICE(te);
    __syncthreads();
#pragma unroll
    for (int eh = 0; eh < 2; ++eh) {
      const int e = 2 * te + eh;
      const int lx = layer * 16 + e;
      // GEMM1: hT[oc][brow], wave tile (it, jn)
      f32x4 acc = f32x4{0.f, 0.f, 0.f, 0.f};
#pragma unroll
      for (int ks = 0; ks < 4; ++ks) {
        size_t fb = ((size_t)((lx * 4 + ks) * 8 + it) * 64 + lane) * 8;
        s16x8 ah = *(const s16x8*)(w1T + fb);
        s16x8 al = *(const s16x8*)(w1T + 524288 + fb);
        int sa = (bsa + ((4 * ks + g) ^ (brow & 7))) * 8;
        s16x8 bh = *(const s16x8*)(sXh + sa);
        s16x8 bl = *(const s16x8*)(sXl + sa);
        acc = MFMA(al, bh, acc);
        acc = MFMA(ah, bl, acc);
        acc = MFMA(ah, bh, acc);
      }
      {  // h epilogue -> sH pair
        f32x4 bv = *(const f32x4*)(b1 + lx * 128 + 16 * it + 4 * g);
        u16x4 hh, hl;
#pragma unroll
        for (int r = 0; r < 4; ++r) {
          float f = fmaxf(acc[r] + bv[r], 0.f);
          u16 h_, l_;
          split2(f, h_, l_);
          hh[r] = h_;
          hl[r] = l_;
        }
        int ha = brow * 128 + 8 * ((2 * it + (g >> 1)) ^ (brow & 7)) + 4 * (g & 1);
        *(u16x4*)(sHh + ha) = hh;
        *(u16x4*)(sHl + ha) = hl;
      }
      __syncthreads();
      // GEMM2: eoT[oc][brow]
      acc = f32x4{0.f, 0.f, 0.f, 0.f};
#pragma unroll
      for (int ks = 0; ks < 4; ++ks) {
        size_t fb = ((size_t)((lx * 4 + ks) * 8 + it) * 64 + lane) * 8;
        s16x8 ah = *(const s16x8*)(w2T + fb);
        s16x8 al = *(const s16x8*)(w2T + 524288 + fb);
        int sa = (bsa + ((4 * ks + g) ^ (brow & 7))) * 8;
        s16x8 bh = *(const s16x8*)(sHh + sa);
        s16x8 bl = *(const s16x8*)(sHl + sa);
        acc = MFMA(al, bh, acc);
        acc = MFMA(ah, bl, acc);
        acc = MFMA(ah, bh, acc);
      }
      {  // eo epilogue -> sEO (granule-4 XOR swizzle)
        f32x4 bv = *(const f32x4*)(b2 + lx * 128 + 16 * it + 4 * g);
        f32x4 ev;
#pragma unroll
        for (int r = 0; r < 4; ++r) ev[r] = fmaxf(acc[r] + bv[r], 0.f);
        int cg = 4 * it + g;
        *(f32x4*)(sEO + brow * 128 + (cg ^ (brow & 7)) * 4) = ev;
      }
      __syncthreads();
      // accumulate: fused[ab][t][ac4*4..+3] += coef * eo[ab][...]
      float ssew = sw[(layer * 8 + te) * 2 + eh];
      f32x4 eov = *(const f32x4*)(sEO + ab * 128 + (ac4 ^ (ab & 7)) * 4);
#pragma unroll
      for (int t = 0; t < 8; ++t) {
        float coef = sG[(t * 16 + e) * 32 + ab] + (t == te ? ssew : 0.f);
#pragma unroll
        for (int r = 0; r < 4; ++r) accf[t][r] = fmaf(coef, eov[r], accf[t][r]);
      }
      // no sync: sEO next overwritten only after the next h-sync
    }
    __syncthreads();  // sX reads + sEO reads done before next stage
  }

  // ---------- output ----------
#pragma unroll
  for (int t = 0; t < 8; ++t)
    *(f32x4*)(xout + ((size_t)(r0 + ab) * 8 + t) * 128 + ac4 * 4) = accf[t];
#undef STAGE_SLICE
}

// ---------------------------------------------------------------------------
extern "C" void kernel_launch(void* const* d_in, const int* in_sizes, int n_in,
                              void* d_out, int out_size, void* d_ws, size_t ws_size,
                              hipStream_t stream) {
  const float* x0 = (const float*)d_in[0];
  const float* w1 = (const float*)d_in[1];
  const float* b1 = (const float*)d_in[2];
  const float* w2 = (const float*)d_in[3];
  const float* b2 = (const float*)d_in[4];
  const float* gw = (const float*)d_in[5];
  const float* gb = (const float*)d_in[6];
  const float* sw = (const float*)d_in[7];

  // ws bytes: w1T pair [0, 2MB) | w2T pair [2MB, 4MB) | gwT pair [4MB, +128KB)
  // | x1f f32 [4.25MB, +128MB)
  u16* w1T = (u16*)d_ws;
  u16* w2T = (u16*)((char*)d_ws + 2097152);
  u16* gwT = (u16*)((char*)d_ws + 4194304);
  float* x1f = (float*)((char*)d_ws + 4456448);
  float* out = (float*)d_out;

  kxform<<<528, 256, 0, stream>>>(w1, w2, gw, w1T, w2T, gwT);
  kfused<<<1024, 1024, 0, stream>>>(x0, x1f, w1T, w2T, gwT, b1, b2, gb, sw, 0);
  kfused<<<1024, 1024, 0, stream>>>(x1f, out, w1T, w2T, gwT, b1, b2, gb, sw, 1);
}

// Round 7
// 458.326 us; speedup vs baseline: 1.7303x; 1.7303x over previous
//
#include <hip/hip_runtime.h>

// AdaTTSp on MI355X. B=32768, T=8, E=2, NE=16, D=H=128, L=2.
// Round 7: fused per-layer kernel, restructured from round 6:
//  - 512 thr (8 waves), 32 rows/block, 2 blocks/CU (LDS 64KB, lb(512,4))
//  - wave = one 16-wide oc tile x 32 rows: 24 MFMA/GEMM between syncs,
//    no weight-fragment duplication across waves
//  - eo accumulated from MFMA fragments into regs (no sEO, no 8-way conflicts)
//  - gate pass: all 8 waves (wave=task), B-frags straight from global
//  - double-buffered sX with stage-ahead; 2 syncs/expert
// Split precision: f32 -> bf16 hi+lo, 3 MFMAs/term (validated r5/r6).

typedef float f32x4 __attribute__((ext_vector_type(4)));
typedef short s16x8 __attribute__((ext_vector_type(8)));
typedef unsigned short u16;
typedef u16 u16x4 __attribute__((ext_vector_type(4)));

#define MFMA(a, b, c) __builtin_amdgcn_mfma_f32_16x16x32_bf16(a, b, c, 0, 0, 0)

__device__ __forceinline__ u16 f2bf(float f) {
  unsigned u = __builtin_bit_cast(unsigned, f);
  return (u16)((u + 0x7FFFu + ((u >> 16) & 1u)) >> 16);  // RNE
}
__device__ __forceinline__ float bf2f(u16 b) {
  unsigned u = ((unsigned)b) << 16;
  return __builtin_bit_cast(float, u);
}
__device__ __forceinline__ void split2(float f, u16& h, u16& l) {
  h = f2bf(f);
  l = f2bf(f - bf2f(h));
}

// ---------------------------------------------------------------------------
// Weight transform -> hi/lo bf16 fragment arrays (identical to round 6).
// w1T/w2T: [q=l*16+e][ks][it][lane][j] (lo at +524288 elems)
//   elem = w[q][d = 32*ks + 8*(lane>>4) + j][m = 16*it + (lane&15)]
// gwT: [q=l*8+t][ks][lane][j] (lo at +32768)
__global__ __launch_bounds__(256) void kxform(
    const float* __restrict__ w1, const float* __restrict__ w2,
    const float* __restrict__ gw, u16* __restrict__ w1T,
    u16* __restrict__ w2T, u16* __restrict__ gwT) {
  int idx = blockIdx.x * 256 + threadIdx.x;
  if (idx < 131072) {
    const float* src = (idx < 65536) ? w1 : w2;
    u16* dst = (idx < 65536) ? w1T : w2T;
    int i = idx & 65535;
    int lane = i & 63;
    int it = (i >> 6) & 7;
    int ks = (i >> 9) & 3;
    int q = i >> 11;
    int g = lane >> 4, le = lane & 15;
    s16x8 vh, vl;
#pragma unroll
    for (int j = 0; j < 8; ++j) {
      float f = src[((size_t)q * 128 + (32 * ks + 8 * g + j)) * 128 + 16 * it + le];
      u16 h, l;
      split2(f, h, l);
      vh[j] = (short)h;
      vl[j] = (short)l;
    }
    *(s16x8*)(dst + (size_t)i * 8) = vh;
    *(s16x8*)(dst + 524288 + (size_t)i * 8) = vl;
  } else {
    int i = idx - 131072;  // 0..4095
    if (i >= 4096) return;
    int lane = i & 63;
    int ks = (i >> 6) & 3;
    int q = (i >> 8) & 15;
    int g = lane >> 4, le = lane & 15;
    s16x8 vh, vl;
#pragma unroll
    for (int j = 0; j < 8; ++j) {
      float f = gw[((size_t)q * 128 + (32 * ks + 8 * g + j)) * 16 + le];
      u16 h, l;
      split2(f, h, l);
      vh[j] = (short)h;
      vl[j] = (short)l;
    }
    *(s16x8*)(gwT + (size_t)i * 8) = vh;
    *(s16x8*)(gwT + 32768 + (size_t)i * 8) = vl;
  }
}

// ---------------------------------------------------------------------------
// Fused layer kernel. grid = B/32 = 1024 blocks, 512 threads (8 waves).
// Wave w = it (oc 16-tile 0..7); j in {0,1} = row 16-tiles; brow = 16j+le.
// LDS x/h tiles: elem [row][c] at row*128 + 8*((c>>3)^(row&7)) + (c&7).
__global__ __launch_bounds__(512, 4) void kfused(
    const float* __restrict__ xin, float* __restrict__ xout,
    const u16* __restrict__ w1T, const u16* __restrict__ w2T,
    const u16* __restrict__ gwT, const float* __restrict__ b1,
    const float* __restrict__ b2, const float* __restrict__ gb,
    const float* __restrict__ sw, int layer) {
  __shared__ u16 sXh[2][4096], sXl[2][4096];  // 32KB (double-buffered x slice)
  __shared__ u16 sHh[4096], sHl[4096];        // 16KB
  __shared__ float sG[4096];                  // [t][e][row] 16KB
  const int tid = threadIdx.x;
  const int lane = tid & 63;
  const int it = tid >> 6;  // wave = oc tile
  const int g = lane >> 4, le = lane & 15;
  const int r0 = blockIdx.x * 32;
  const int srow = tid >> 4, sc8 = tid & 15;

  auto stage = [&](int buf, int te) {
    const float* p = xin + ((size_t)(r0 + srow) * 8 + te) * 128 + sc8 * 8;
    f32x4 f0 = *(const f32x4*)p;
    f32x4 f1 = *(const f32x4*)(p + 4);
    s16x8 vh, vl;
#pragma unroll
    for (int z = 0; z < 4; ++z) {
      u16 h_, l_;
      split2(f0[z], h_, l_);
      vh[z] = (short)h_;
      vl[z] = (short)l_;
      split2(f1[z], h_, l_);
      vh[4 + z] = (short)h_;
      vl[4 + z] = (short)l_;
    }
    int sa = srow * 128 + 8 * (sc8 ^ (srow & 7));
    *(s16x8*)(&sXh[buf][sa]) = vh;
    *(s16x8*)(&sXl[buf][sa]) = vl;
  };

  // ---- stage slice 0 (overlaps gate pass) ----
  stage(0, 0);

  // ---- gate pass: wave = task t = it; B-frags straight from global ----
  {
    const int t = it;
    const int lt = layer * 8 + t;
    f32x4 lacc[2];
    lacc[0] = f32x4{0.f, 0.f, 0.f, 0.f};
    lacc[1] = f32x4{0.f, 0.f, 0.f, 0.f};
#pragma unroll
    for (int ks = 0; ks < 4; ++ks) {
      size_t fb = ((size_t)(lt * 4 + ks) * 64 + lane) * 8;
      s16x8 ah = *(const s16x8*)(gwT + fb);
      s16x8 al = *(const s16x8*)(gwT + 32768 + fb);
#pragma unroll
      for (int j = 0; j < 2; ++j) {
        const float* p =
            xin + ((size_t)(r0 + 16 * j + le) * 8 + t) * 128 + 32 * ks + 8 * g;
        f32x4 f0 = *(const f32x4*)p;
        f32x4 f1 = *(const f32x4*)(p + 4);
        s16x8 bh, bl;
#pragma unroll
        for (int z = 0; z < 4; ++z) {
          u16 h_, l_;
          split2(f0[z], h_, l_);
          bh[z] = (short)h_;
          bl[z] = (short)l_;
          split2(f1[z], h_, l_);
          bh[4 + z] = (short)h_;
          bl[4 + z] = (short)l_;
        }
        lacc[j] = MFMA(al, bh, lacc[j]);
        lacc[j] = MFMA(ah, bl, lacc[j]);
        lacc[j] = MFMA(ah, bh, lacc[j]);
      }
    }
    // C: row(4g+r) = e, col(le) = brow. Softmax over e (in-lane r + g groups).
#pragma unroll
    for (int j = 0; j < 2; ++j) {
      float zb[4];
#pragma unroll
      for (int r = 0; r < 4; ++r) zb[r] = lacc[j][r] + gb[lt * 16 + 4 * g + r];
      float m4 = fmaxf(fmaxf(zb[0], zb[1]), fmaxf(zb[2], zb[3]));
      m4 = fmaxf(m4, __shfl_xor(m4, 16, 64));
      m4 = fmaxf(m4, __shfl_xor(m4, 32, 64));
      float p4[4], s4 = 0.f;
#pragma unroll
      for (int r = 0; r < 4; ++r) {
        p4[r] = __expf(zb[r] - m4);
        s4 += p4[r];
      }
      s4 += __shfl_xor(s4, 16, 64);
      s4 += __shfl_xor(s4, 32, 64);
      float inv = 1.f / s4;
#pragma unroll
      for (int r = 0; r < 4; ++r)
        sG[(t * 16 + 4 * g + r) * 32 + 16 * j + le] = p4[r] * inv;
    }
  }
  __syncthreads();

  // ---- expert loop: 2 syncs/expert, eo accumulated in registers ----
  f32x4 accf[8][2];
#pragma unroll
  for (int t = 0; t < 8; ++t)
#pragma unroll
    for (int j = 0; j < 2; ++j) accf[t][j] = f32x4{0.f, 0.f, 0.f, 0.f};

  for (int e = 0; e < 16; ++e) {
    const int te = e >> 1, eh = e & 1, cb = te & 1;
    const int lx = layer * 16 + e;
    // ---- interval A: GEMM1 (hT = w1^T x^T) + h epilogue ----
    f32x4 acc[2];
    acc[0] = f32x4{0.f, 0.f, 0.f, 0.f};
    acc[1] = f32x4{0.f, 0.f, 0.f, 0.f};
#pragma unroll
    for (int ks = 0; ks < 4; ++ks) {
      size_t fb = ((size_t)((lx * 4 + ks) * 8 + it) * 64 + lane) * 8;
      s16x8 ah = *(const s16x8*)(w1T + fb);
      s16x8 al = *(const s16x8*)(w1T + 524288 + fb);
#pragma unroll
      for (int j = 0; j < 2; ++j) {
        int brow = 16 * j + le;
        int sa = brow * 128 + 8 * ((4 * ks + g) ^ (brow & 7));
        s16x8 bh = *(const s16x8*)(&sXh[cb][sa]);
        s16x8 bl = *(const s16x8*)(&sXl[cb][sa]);
        acc[j] = MFMA(al, bh, acc[j]);
        acc[j] = MFMA(ah, bl, acc[j]);
        acc[j] = MFMA(ah, bh, acc[j]);
      }
    }
    {
      f32x4 bv = *(const f32x4*)(b1 + lx * 128 + 16 * it + 4 * g);
#pragma unroll
      for (int j = 0; j < 2; ++j) {
        int brow = 16 * j + le;
        u16x4 hh, hl;
#pragma unroll
        for (int r = 0; r < 4; ++r) {
          float f = fmaxf(acc[j][r] + bv[r], 0.f);
          u16 h_, l_;
          split2(f, h_, l_);
          hh[r] = h_;
          hl[r] = l_;
        }
        int ha = brow * 128 + 8 * ((2 * it + (g >> 1)) ^ (brow & 7)) + 4 * (g & 1);
        *(u16x4*)(&sHh[ha]) = hh;
        *(u16x4*)(&sHl[ha]) = hl;
      }
    }
    __syncthreads();
    // ---- interval B: GEMM2 (eoT = w2^T h^T) + reg accumulate + stage-ahead
    acc[0] = f32x4{0.f, 0.f, 0.f, 0.f};
    acc[1] = f32x4{0.f, 0.f, 0.f, 0.f};
#pragma unroll
    for (int ks = 0; ks < 4; ++ks) {
      size_t fb = ((size_t)((lx * 4 + ks) * 8 + it) * 64 + lane) * 8;
      s16x8 ah = *(const s16x8*)(w2T + fb);
      s16x8 al = *(const s16x8*)(w2T + 524288 + fb);
#pragma unroll
      for (int j = 0; j < 2; ++j) {
        int brow = 16 * j + le;
        int sa = brow * 128 + 8 * ((4 * ks + g) ^ (brow & 7));
        s16x8 bh = *(const s16x8*)(&sHh[sa]);
        s16x8 bl = *(const s16x8*)(&sHl[sa]);
        acc[j] = MFMA(al, bh, acc[j]);
        acc[j] = MFMA(ah, bl, acc[j]);
        acc[j] = MFMA(ah, bh, acc[j]);
      }
    }
    {
      f32x4 bv = *(const f32x4*)(b2 + lx * 128 + 16 * it + 4 * g);
      float ssew = sw[(layer * 8 + te) * 2 + eh];
#pragma unroll
      for (int j = 0; j < 2; ++j) {
        int brow = 16 * j + le;
        f32x4 ev;
#pragma unroll
        for (int r = 0; r < 4; ++r) ev[r] = fmaxf(acc[j][r] + bv[r], 0.f);
#pragma unroll
        for (int t = 0; t < 8; ++t) {
          float coef = sG[(t * 16 + e) * 32 + brow] + (t == te ? ssew : 0.f);
#pragma unroll
          for (int r = 0; r < 4; ++r)
            accf[t][j][r] = fmaf(coef, ev[r], accf[t][j][r]);
        }
      }
    }
    if (eh == 0 && te < 7) stage(cb ^ 1, te + 1);
    __syncthreads();
  }

  // ---- output: accf[t][j] holds out[r0+16j+le][t][16it+4g .. +3] ----
#pragma unroll
  for (int t = 0; t < 8; ++t)
#pragma unroll
    for (int j = 0; j < 2; ++j)
      *(f32x4*)(xout + ((size_t)(r0 + 16 * j + le) * 8 + t) * 128 + 16 * it +
                4 * g) = accf[t][j];
}

// ---------------------------------------------------------------------------
extern "C" void kernel_launch(void* const* d_in, const int* in_sizes, int n_in,
                              void* d_out, int out_size, void* d_ws, size_t ws_size,
                              hipStream_t stream) {
  const float* x0 = (const float*)d_in[0];
  const float* w1 = (const float*)d_in[1];
  const float* b1 = (const float*)d_in[2];
  const float* w2 = (const float*)d_in[3];
  const float* b2 = (const float*)d_in[4];
  const float* gw = (const float*)d_in[5];
  const float* gb = (const float*)d_in[6];
  const float* sw = (const float*)d_in[7];

  // ws bytes: w1T pair [0,2MB) | w2T pair [2MB,4MB) | gwT pair [4MB,+128KB)
  // | x1f f32 [4.25MB, +128MB)
  u16* w1T = (u16*)d_ws;
  u16* w2T = (u16*)((char*)d_ws + 2097152);
  u16* gwT = (u16*)((char*)d_ws + 4194304);
  float* x1f = (float*)((char*)d_ws + 4456448);
  float* out = (float*)d_out;

  kxform<<<528, 256, 0, stream>>>(w1, w2, gw, w1T, w2T, gwT);
  kfused<<<1024, 512, 0, stream>>>(x0, x1f, w1T, w2T, gwT, b1, b2, gb, sw, 0);
  kfused<<<1024, 512, 0, stream>>>(x1f, out, w1T, w2T, gwT, b1, b2, gb, sw, 1);
}